// Round 3
// baseline (1456.580 us; speedup 1.0000x reference)
//
#include <hip/hip_runtime.h>
#include <stdint.h>

using u16 = unsigned short;
using u32 = unsigned int;

typedef short bf8_t __attribute__((ext_vector_type(8)));   // 8 bf16 values (4 VGPRs)
typedef float f4_t  __attribute__((ext_vector_type(4)));

// ---------- helpers ----------
__device__ __forceinline__ u16 f2bf(float f) {
  u32 u = __float_as_uint(f);
  u32 r = (u + 0x7FFFu + ((u >> 16) & 1u)) >> 16;   // RNE
  return (u16)r;
}

__device__ __forceinline__ void cp16(const void* g, void* l) {
  // async global->LDS, 16B per lane; LDS dest = wave-uniform base + lane*16
  __builtin_amdgcn_global_load_lds(
      (const __attribute__((address_space(1))) u32*)g,
      (__attribute__((address_space(3))) u32*)l, 16, 0, 0);
}

// JAX threefry2x32, key = (0, 42)  [jax.random.key(42)]
__device__ __forceinline__ void threefry_0_42(u32 x0, u32 x1, u32& o0, u32& o1) {
  const u32 k0 = 0u, k1 = 42u;
  const u32 k2 = 0x1BD11BDAu ^ k0 ^ k1;
#define TFR(r) { x0 += x1; x1 = (x1 << r) | (x1 >> (32 - r)); x1 ^= x0; }
  x0 += k0; x1 += k1;
  TFR(13) TFR(15) TFR(26) TFR(6)   x0 += k1; x1 += k2 + 1u;
  TFR(17) TFR(29) TFR(16) TFR(24)  x0 += k2; x1 += k0 + 2u;
  TFR(13) TFR(15) TFR(26) TFR(6)   x0 += k0; x1 += k1 + 3u;
  TFR(17) TFR(29) TFR(16) TFR(24)  x0 += k1; x1 += k2 + 4u;
  TFR(13) TFR(15) TFR(26) TFR(6)   x0 += k2; x1 += k0 + 5u;
#undef TFR
  o0 = x0; o1 = x1;
}

// ---------- conversion / padding ----------
__global__ __launch_bounds__(256)
void cvt_bf16(const float* __restrict__ s, u16* __restrict__ d, int n4) {
  const int i = blockIdx.x * 256 + threadIdx.x;
  if (i >= n4) return;
  const float4 v = ((const float4*)s)[i];
  ushort4 o;
  o.x = f2bf(v.x); o.y = f2bf(v.y); o.z = f2bf(v.z); o.w = f2bf(v.w);
  ((ushort4*)d)[i] = o;
}

__global__ __launch_bounds__(256)
void pad_cls(const float* __restrict__ src, u16* __restrict__ dst) {
  const int i = blockIdx.x * 256 + threadIdx.x;      // 32*2048
  const int row = i >> 11, col = i & 2047;
  dst[i] = (row < 21) ? f2bf(src[row * 2048 + col]) : (u16)0;
}

__global__ __launch_bounds__(256)
void pad_head(const float* __restrict__ cf, const float* __restrict__ mk,
              u16* __restrict__ dst) {
  const int i = blockIdx.x * 256 + threadIdx.x;      // 32*1024
  const int row = i >> 10, col = i & 1023;
  float v = 0.0f;
  if (row < 22)      v = cf[row * 1024 + col];
  else if (row < 24) v = mk[(row - 22) * 1024 + col];
  dst[i] = f2bf(v);
}

__global__ __launch_bounds__(256)
void init_h(u16* __restrict__ hbf, float* __restrict__ h32) {
  const int i = blockIdx.x * 256 + threadIdx.x;      // 128*1024
  hbf[i] = 0;
  h32[i] = 0.0f;
}

// ---------- big GEMM: C[M,N] = A[M,K] * B[N,K]^T (+bias, opt relu) ----------
// 128x128 tile, BK=64, 256 threads (4 waves as 2x2 of 64x64)
template<int RELU>
__global__ __launch_bounds__(256)
void gemm128(const u16* __restrict__ A, const u16* __restrict__ Bw,
             const float* __restrict__ bias, float* __restrict__ C,
             int N, int K) {
  __shared__ __align__(16) u16 As[128 * 64];
  __shared__ __align__(16) u16 Bs[128 * 64];
  const int tid = threadIdx.x;
  const int wv = tid >> 6, lane = tid & 63;
  const int wm = wv >> 1, wn = wv & 1;
  const u16* Ab = A + (size_t)blockIdx.x * 128 * K;
  const u16* Bb = Bw + (size_t)blockIdx.y * 128 * K;
  const int lr = lane >> 3, lc = lane & 7;
  f4_t acc[4][4] = {};
  for (int k0 = 0; k0 < K; k0 += 64) {
#pragma unroll
    for (int i = 0; i < 4; ++i) {
      const int row = wv * 32 + i * 8;
      cp16(Ab + (size_t)(row + lr) * K + (k0 + lc * 8), &As[row * 64]);
      cp16(Bb + (size_t)(row + lr) * K + (k0 + lc * 8), &Bs[row * 64]);
    }
    __syncthreads();
#pragma unroll
    for (int kk = 0; kk < 2; ++kk) {
      bf8_t av[4], bv[4];
#pragma unroll
      for (int mt = 0; mt < 4; ++mt)
        av[mt] = *(const bf8_t*)&As[(wm * 64 + mt * 16 + (lane & 15)) * 64 + kk * 32 + (lane >> 4) * 8];
#pragma unroll
      for (int nt = 0; nt < 4; ++nt)
        bv[nt] = *(const bf8_t*)&Bs[(wn * 64 + nt * 16 + (lane & 15)) * 64 + kk * 32 + (lane >> 4) * 8];
#pragma unroll
      for (int mt = 0; mt < 4; ++mt)
#pragma unroll
        for (int nt = 0; nt < 4; ++nt)
          acc[mt][nt] = __builtin_amdgcn_mfma_f32_16x16x32_bf16(av[mt], bv[nt], acc[mt][nt], 0, 0, 0);
    }
    __syncthreads();
  }
  const int q = lane >> 4, cn = lane & 15;
#pragma unroll
  for (int mt = 0; mt < 4; ++mt) {
#pragma unroll
    for (int nt = 0; nt < 4; ++nt) {
      const int col = blockIdx.y * 128 + wn * 64 + nt * 16 + cn;
      const float bb = bias[col];
#pragma unroll
      for (int r = 0; r < 4; ++r) {
        const int row = blockIdx.x * 128 + wm * 64 + mt * 16 + q * 4 + r;
        float v = acc[mt][nt][r] + bb;
        if (RELU) v = fmaxf(v, 0.0f);
        C[(size_t)row * N + col] = v;
      }
    }
  }
}

// ---------- skinny GEMM: C[M,32] = A[M,K] * B[32,K]^T, M-tile 64 ----------
// HEAD=0: vl_preds (cols<21, +cls_b). HEAD=1: enc (cols<22,+cf_b) / mask (cols 22..23,+mk_b)
template<int HEAD>
__global__ __launch_bounds__(256)
void gemm_skinny(const u16* __restrict__ A, const u16* __restrict__ Bw,
                 const float* __restrict__ bias, const float* __restrict__ bias2,
                 float* __restrict__ C0, float* __restrict__ C1, int K) {
  __shared__ __align__(16) u16 As[64 * 64];
  __shared__ __align__(16) u16 Bs[32 * 64];
  const int tid = threadIdx.x, wv = tid >> 6, lane = tid & 63;
  const u16* Ab = A + (size_t)blockIdx.x * 64 * K;
  const int lr = lane >> 3, lc = lane & 7;
  f4_t acc[2] = {};
  for (int k0 = 0; k0 < K; k0 += 64) {
#pragma unroll
    for (int i = 0; i < 2; ++i) {
      const int row = wv * 16 + i * 8;
      cp16(Ab + (size_t)(row + lr) * K + (k0 + lc * 8), &As[row * 64]);
    }
    {
      const int row = wv * 8;
      cp16(Bw + (size_t)(row + lr) * K + (k0 + lc * 8), &Bs[row * 64]);
    }
    __syncthreads();
#pragma unroll
    for (int kk = 0; kk < 2; ++kk) {
      bf8_t a = *(const bf8_t*)&As[(wv * 16 + (lane & 15)) * 64 + kk * 32 + (lane >> 4) * 8];
#pragma unroll
      for (int nt = 0; nt < 2; ++nt) {
        bf8_t b = *(const bf8_t*)&Bs[(nt * 16 + (lane & 15)) * 64 + kk * 32 + (lane >> 4) * 8];
        acc[nt] = __builtin_amdgcn_mfma_f32_16x16x32_bf16(a, b, acc[nt], 0, 0, 0);
      }
    }
    __syncthreads();
  }
  const int q = lane >> 4, cn = lane & 15;
#pragma unroll
  for (int nt = 0; nt < 2; ++nt) {
    const int col = nt * 16 + cn;
#pragma unroll
    for (int r = 0; r < 4; ++r) {
      const int row = blockIdx.x * 64 + wv * 16 + q * 4 + r;
      const float v = acc[nt][r];
      if (HEAD) {
        if (col < 22)      C0[(size_t)row * 22 + col] = v + bias[col];
        else if (col < 24) C1[(size_t)row * 2 + (col - 22)] = v + bias2[col - 22];
      } else {
        if (col < 21)      C0[(size_t)row * 21 + col] = v + bias[col];
      }
    }
  }
}

// ---------- dropout: JAX threefry bernoulli, key 42, p_keep=0.7 ----------
// PARTITIONABLE threefry, bit_width=32 (jax/_src/prng.py):
//   counts1, counts2 = hi/lo words of uint64 iota  -> (0, j) here (size < 2^32)
//   bits1, bits2 = threefry2x32(key, counts1, counts2)
//   bits = bits1 ^ bits2          <-- the 32-bit path XORs both output words
// [R1: legacy pair (j, j+2^23) -> absmax 0.486; R2: o1-only -> 0.475; both are
//  the wrong-mask decorrelation signature (~0.47). XOR is the actual JAX path.]
__global__ __launch_bounds__(256)
void dropout_kernel(float* __restrict__ x, u16* __restrict__ xbf) {
  const u32 tid = blockIdx.x * 256u + threadIdx.x;   // 2^22 threads
  const u32 j0 = tid * 4u;
  float4 a = *(const float4*)(x + j0);
  float av[4] = {a.x, a.y, a.z, a.w};
  u16 abf[4];
#pragma unroll
  for (int i = 0; i < 4; ++i) {
    u32 o0, o1;
    threefry_0_42(0u, j0 + (u32)i, o0, o1);
    const u32 bits = o0 ^ o1;
    const float u1 = __uint_as_float((bits >> 9) | 0x3f800000u) - 1.0f;
    av[i] = (u1 < 0.7f) ? av[i] * (1.0f / 0.7f) : 0.0f;
    abf[i] = f2bf(av[i]);
  }
  float4 oa; oa.x = av[0]; oa.y = av[1]; oa.z = av[2]; oa.w = av[3];
  *(float4*)(x + j0) = oa;
  ushort4 ua; ua.x = abf[0]; ua.y = abf[1]; ua.z = abf[2]; ua.w = abf[3];
  *(ushort4*)(xbf + j0) = ua;
}

// ---------- one GRU step ----------
// grid (32 col-blocks of 32 hid cols, 4 seq-blocks of 32 seqs); 256 threads.
// Computes G = h_prev @ whh_slab^T (slab rows: [r | z | n] x 32 cols), then gates.
__global__ __launch_bounds__(256)
void gru_step(const u16* __restrict__ hin, u16* __restrict__ hout,
              float* __restrict__ h32, const u16* __restrict__ whh,
              const float* __restrict__ gi, const float* __restrict__ bhh,
              u16* __restrict__ hrbf, int t) {
  __shared__ __align__(16) u16 As[32 * 128];    // h chunk [32 seq][128 k]
  __shared__ __align__(16) u16 Bs[96 * 128];    // weight chunk [96 rows][128 k]
  __shared__ float Gs[32 * 96];
  const int tid = threadIdx.x, wv = tid >> 6, lane = tid & 63;
  const int cb = blockIdx.x, sb = blockIdx.y;
  const int wm = wv & 1, wn = wv >> 1;
  const int lr4 = lane >> 4, lc16 = lane & 15;
  f4_t acc[3] = {};
  for (int kc = 0; kc < 8; ++kc) {
    const int k0 = kc * 128;
#pragma unroll
    for (int i = 0; i < 2; ++i) {
      const int row = wv * 8 + i * 4;
      cp16(hin + (size_t)(sb * 32 + row + lr4) * 1024 + (k0 + lc16 * 8), &As[row * 128]);
    }
#pragma unroll
    for (int i = 0; i < 6; ++i) {
      const int lrow = wv * 24 + i * 4;
      const int lrl = lrow + lr4;
      const int sec = lrl >> 5;                       // 0:r 1:z 2:n
      const int grow = sec * 1024 + cb * 32 + (lrl & 31);
      cp16(whh + (size_t)grow * 1024 + (k0 + lc16 * 8), &Bs[lrow * 128]);
    }
    __syncthreads();
#pragma unroll
    for (int kk = 0; kk < 4; ++kk) {
      bf8_t a = *(const bf8_t*)&As[(wm * 16 + (lane & 15)) * 128 + kk * 32 + (lane >> 4) * 8];
#pragma unroll
      for (int nt = 0; nt < 3; ++nt) {
        bf8_t b = *(const bf8_t*)&Bs[(wn * 48 + nt * 16 + (lane & 15)) * 128 + kk * 32 + (lane >> 4) * 8];
        acc[nt] = __builtin_amdgcn_mfma_f32_16x16x32_bf16(a, b, acc[nt], 0, 0, 0);
      }
    }
    __syncthreads();
  }
  const int q = lane >> 4, cn = lane & 15;
#pragma unroll
  for (int nt = 0; nt < 3; ++nt)
#pragma unroll
    for (int r = 0; r < 4; ++r)
      Gs[(wm * 16 + q * 4 + r) * 96 + wn * 48 + nt * 16 + cn] = acc[nt][r];
  __syncthreads();
#pragma unroll
  for (int ii = 0; ii < 4; ++ii) {
    const int item = ii * 256 + tid;
    const int m = item >> 5, j = item & 31;
    const int seq = sb * 32 + m, col = cb * 32 + j;
    const int girow = (seq >> 3) * 512 + (seq & 7) * 64 + t;
    const float* gir = gi + (size_t)girow * 3072;
    const float gr = Gs[m * 96 + j]      + bhh[col]        + gir[col];
    const float gz = Gs[m * 96 + 32 + j] + bhh[1024 + col] + gir[1024 + col];
    const float gh = Gs[m * 96 + 64 + j] + bhh[2048 + col];   // h_n incl. b_hh (multiplied by r!)
    const float gn = gir[2048 + col];
    const float rr = 1.0f / (1.0f + __expf(-gr));
    const float zz = 1.0f / (1.0f + __expf(-gz));
    float targ = gn + rr * gh;
    targ = fminf(fmaxf(targ, -15.0f), 15.0f);
    const float e2 = __expf(2.0f * targ);
    const float nn = (e2 - 1.0f) / (e2 + 1.0f);
    const float hp = h32[(size_t)seq * 1024 + col];
    const float h = (1.0f - zz) * nn + zz * hp;
    h32[(size_t)seq * 1024 + col] = h;
    hout[(size_t)seq * 1024 + col] = f2bf(h);
    hrbf[((size_t)t * 128 + seq) * 1024 + col] = f2bf(fmaxf(h, 0.0f));
  }
}

// ---------- host ----------
extern "C" void kernel_launch(void* const* d_in, const int* in_sizes, int n_in,
                              void* d_out, int out_size, void* d_ws, size_t ws_size,
                              hipStream_t stream) {
  const float* feats = (const float*)d_in[0];
  const float* fc_w  = (const float*)d_in[1];
  const float* fc_b  = (const float*)d_in[2];
  const float* cls_w = (const float*)d_in[3];
  const float* cls_b = (const float*)d_in[4];
  const float* w_ih  = (const float*)d_in[5];
  const float* w_hh  = (const float*)d_in[6];
  const float* b_ih  = (const float*)d_in[7];
  const float* b_hh  = (const float*)d_in[8];
  const float* cf_w  = (const float*)d_in[9];
  const float* cf_b  = (const float*)d_in[10];
  const float* mk_w  = (const float*)d_in[11];
  const float* mk_b  = (const float*)d_in[12];

  char* ws = (char*)d_ws;
  size_t off = 0;
  auto alloc = [&](size_t b) { char* p = ws + off; off += (b + 255) & ~(size_t)255; return p; };
  u16*  featsbf = (u16*)alloc((size_t)8192 * 2048 * 2);
  u16*  xbf     = featsbf;                 // alias: feats_bf dead after fc GEMM
  u16*  fcwbf   = (u16*)alloc((size_t)2048 * 2048 * 2);
  u16*  wihbf   = (u16*)alloc((size_t)3072 * 2048 * 2);
  u16*  whhbf   = (u16*)alloc((size_t)3072 * 1024 * 2);
  u16*  clsp    = (u16*)alloc((size_t)32 * 2048 * 2);
  u16*  headp   = (u16*)alloc((size_t)32 * 1024 * 2);
  float* gi     = (float*)alloc((size_t)8192 * 3072 * 4);
  float* h32    = (float*)alloc((size_t)128 * 1024 * 4);
  u16*  hbf0    = (u16*)alloc((size_t)128 * 1024 * 2);
  u16*  hbf1    = (u16*)alloc((size_t)128 * 1024 * 2);
  u16*  hrbf    = (u16*)alloc((size_t)8192 * 1024 * 2);

  float* out_enc  = (float*)d_out;                       // [8192,22]
  float* out_mask = out_enc + (size_t)8192 * 22;         // [8192,2]
  float* out_x    = out_mask + (size_t)8192 * 2;         // [16,512,2048]
  float* out_vl   = out_x + (size_t)8192 * 2048;         // [16,512,21]

  cvt_bf16<<<16384, 256, 0, stream>>>(feats, featsbf, 4194304);
  cvt_bf16<<<4096, 256, 0, stream>>>(fc_w, fcwbf, 1048576);
  cvt_bf16<<<6144, 256, 0, stream>>>(w_ih, wihbf, 1572864);
  cvt_bf16<<<3072, 256, 0, stream>>>(w_hh, whhbf, 786432);
  pad_cls<<<256, 256, 0, stream>>>(cls_w, clsp);
  pad_head<<<128, 256, 0, stream>>>(cf_w, mk_w, headp);

  // x_pre = relu(feats @ fc_w^T + fc_b) -> out_x (fp32)
  gemm128<1><<<dim3(64, 16), 256, 0, stream>>>(featsbf, fcwbf, fc_b, out_x, 2048, 2048);
  // in-place dropout on out_x; also writes bf16 x into ws
  dropout_kernel<<<16384, 256, 0, stream>>>(out_x, xbf);
  // vl_preds
  gemm_skinny<0><<<128, 256, 0, stream>>>(xbf, clsp, cls_b, nullptr, out_vl, nullptr, 2048);
  // gi = x @ w_ih^T + b_ih   (b_hh NOT folded: n-gate needs r*(gh+b_hh))
  gemm128<0><<<dim3(64, 24), 256, 0, stream>>>(xbf, wihbf, b_ih, gi, 3072, 2048);

  init_h<<<512, 256, 0, stream>>>(hbf0, h32);
  for (int t = 0; t < 64; ++t) {
    const u16* hin = (t & 1) ? hbf1 : hbf0;
    u16* hout = (t & 1) ? hbf0 : hbf1;
    gru_step<<<dim3(32, 4), 256, 0, stream>>>(hin, hout, h32, whhbf, gi, b_hh, hrbf, t);
  }
  // heads: enc_scores + mask_scores
  gemm_skinny<1><<<128, 256, 0, stream>>>(hrbf, headp, cf_b, mk_b, out_enc, out_mask, 1024);
}